// Round 4
// baseline (358.777 us; speedup 1.0000x reference)
//
#include <hip/hip_runtime.h>
#include <math.h>

// Problem constants
#define B_N 2048
#define T_N 128
#define C_N 3
#define J_N 25
#define E_N 64
#define TC  (T_N*C_N)    // 384 rows per batch
#define TCJ (TC*J_N)     // 9600 floats per batch
#define NQ4 (TCJ/4)      // 2400 float4 per batch

// Workspace layout (float offsets). Total ~16.3 MiB.
#define D_OFF      0                      // D [2048*2048] f32 (raw-h distances)
#define H_OFF      (B_N*B_N)              // h [2048*25] (raw)
#define BLO_OFF    (H_OFF + B_N*J_N)      // per-block lo [2048]
#define BHI_OFF    (BLO_OFF + B_N)        // per-block hi [2048]
#define COMP_OFF   (BHI_OFF + B_N)        // u32 comp[2048]
#define CNT_OFF    (COMP_OFF + B_N)       // u32 edge counter
#define TICKET_OFF (CNT_OFF + 1)          // u32 ticket
#define DEATHS_OFF (TICKET_OFF + 1)       // f32 deaths[2047]
#define CBEST_OFF  (DEATHS_OFF + B_N)     // u64 cbest[2048] (even offset -> 8B aligned)

typedef unsigned long long u64;
#define U64MAX 0xFFFFFFFFFFFFFFFFull

// One block per batch. Coalesced float4 grid-stride (stride 250 preserves
// j-residue mod 25), register accumulate, tiny LDS reduce. Also piggybacks
// MST state init and per-block lo/hi (no atomics, no k_init).
__global__ void __launch_bounds__(256) k_reduce(const float* __restrict__ x,
                                                float* __restrict__ ws) {
    __shared__ float4 part[250];
    __shared__ float S[100];
    __shared__ float Mj[25];
    const int t = threadIdx.x, b = blockIdx.x;
    if (t == 0) {
        ((unsigned*)(ws + COMP_OFF))[b] = (unsigned)b;
        ((u64*)(ws + CBEST_OFF))[b] = U64MAX;
        if (b == 0) {
            *(unsigned*)(ws + CNT_OFF) = 0u;
            *(unsigned*)(ws + TICKET_OFF) = 0u;
        }
    }
    const float4* x4 = (const float4*)(x + (size_t)b * TCJ);
    if (t < 250) {
        float4 a; a.x = a.y = a.z = a.w = 0.f;
        for (int idx = t; idx < NQ4; idx += 250) {
            float4 v = x4[idx];
            a.x += v.x; a.y += v.y; a.z += v.z; a.w += v.w;
        }
        part[t] = a;
    }
    __syncthreads();
    if (t < 25) {
        float4 s = part[t];
        #pragma unroll
        for (int g = 1; g < 10; ++g) {
            float4 v = part[t + 25 * g];
            s.x += v.x; s.y += v.y; s.z += v.z; s.w += v.w;
        }
        // S[k] = sum over batch of elements with flat index ≡ k (mod 100)
        S[4*t] = s.x; S[4*t+1] = s.y; S[4*t+2] = s.z; S[4*t+3] = s.w;
    }
    __syncthreads();
    if (t < 25) Mj[t] = (S[t] + S[t+25] + S[t+50] + S[t+75]) * (1.0f / 384.0f);
    __syncthreads();
    if (t < 25) {
        float mj = Mj[t], acc = 0.f;
        #pragma unroll
        for (int i = 0; i < J_N; ++i) { float d = Mj[i] - mj; acc += d * d; }
        float hv = sqrtf(acc);
        ws[H_OFF + b * J_N + t] = hv;
        S[t] = hv;
    }
    __syncthreads();
    if (t == 0) {
        float lo = S[0], hi = S[0];
        #pragma unroll
        for (int i = 1; i < J_N; ++i) { lo = fminf(lo, S[i]); hi = fmaxf(hi, S[i]); }
        ws[BLO_OFF + b] = lo;
        ws[BHI_OFF + b] = hi;
    }
}

// 16x16 tile of the 2048x2048 raw-h distance matrix per block.
// (Min-max normalization is the same affine map per coordinate -> distances
//  scale uniformly by rinv; MST is scale-invariant, rinv applied in k_struct.)
__global__ void k_dist(float* ws) {
    __shared__ float A[16][26], Bsh[16][26];
    const int tx = threadIdx.x, ty = threadIdx.y;
    const int flat = ty * 16 + tx;
    const int rowA = blockIdx.x * 16, rowB = blockIdx.y * 16;
    const float* h = ws + H_OFF;
    for (int idx = flat; idx < 16 * J_N; idx += 256) {
        int r = idx / J_N, c = idx % J_N;
        A[r][c]   = h[(rowA + r) * J_N + c];
        Bsh[r][c] = h[(rowB + r) * J_N + c];
    }
    __syncthreads();
    float acc = 0.f;
    #pragma unroll
    for (int k = 0; k < J_N; ++k) {
        float d = A[ty][k] - Bsh[tx][k];
        acc += d * d;
    }
    float* D = ws + D_OFF;
    D[(size_t)(rowA + ty) * B_N + rowB + tx] = sqrtf(fmaxf(acc, 1e-12f));
}

// One Boruvka round, fused scan+union. 256 blocks x 1024 threads; each block
// scans 8 rows (2 waves/row), atomicMin into cbest[comp[row]]. Last block to
// arrive (ticket) performs the union with its 1024 threads (LDS pointer jump).
// Cross-round visibility rides kernel-launch boundaries; in-kernel cbest reads
// in the union use no-op atomicMin to hit the device-coherent point.
__global__ void __launch_bounds__(1024) k_round(float* __restrict__ ws) {
    unsigned* gcnt = (unsigned*)(ws + CNT_OFF);
    if (*gcnt >= B_N - 1) return;   // converged: uniform early-exit
    const int t = threadIdx.x;
    const int w = t >> 6, lane = t & 63;
    const int row = blockIdx.x * 8 + (w >> 1);
    const int half = w & 1;
    unsigned* comp = (unsigned*)(ws + COMP_OFF);
    u64* cbest = (u64*)(ws + CBEST_OFF);
    const unsigned ci = comp[row];
    const float4* row4 = (const float4*)(ws + D_OFF + (size_t)row * B_N);
    const uint4* comp4 = (const uint4*)comp;
    u64 best = U64MAX;
    #pragma unroll
    for (int k = 0; k < 4; ++k) {
        const int q = half * 256 + k * 64 + lane;   // float4 index within row
        float4 w4 = row4[q];
        uint4  c4 = comp4[q];
        const unsigned j0 = (unsigned)(q * 4);
        float wv[4] = {w4.x, w4.y, w4.z, w4.w};
        unsigned cv[4] = {c4.x, c4.y, c4.z, c4.w};
        #pragma unroll
        for (int m = 0; m < 4; ++m) {
            if (cv[m] != ci) {
                unsigned j = j0 + m;
                unsigned a = min((unsigned)row, j), b2 = max((unsigned)row, j);
                u64 key = ((u64)__float_as_uint(wv[m]) << 32) | (a << 11) | b2;
                if (key < best) best = key;
            }
        }
    }
    #pragma unroll
    for (int off = 32; off; off >>= 1) {
        u64 o = __shfl_down(best, off);
        if (o < best) best = o;
    }
    if (lane == 0 && best != U64MAX) atomicMin(&cbest[ci], best);
    __threadfence();                // drain this thread's atomics to coherence
    __shared__ unsigned islast;
    __syncthreads();
    if (t == 0) {
        unsigned prev = atomicAdd((unsigned*)(ws + TICKET_OFF), 1u);
        islast = (prev == gridDim.x - 1) ? 1u : 0u;
    }
    __syncthreads();
    if (!islast) return;

    // ---- union (last block only) ----
    __shared__ unsigned par[B_N];
    __shared__ unsigned cnt_s;
    float* deaths = ws + DEATHS_OFF;
    const unsigned base = *gcnt;
    if (t == 0) cnt_s = 0u;
    __syncthreads();
    // Phase 1: hook + dedup + edge append (cbest reads via coherent atomics)
    #pragma unroll
    for (int c = t; c < B_N; c += 1024) {
        u64 k = atomicMin(&cbest[c], U64MAX);
        unsigned p = (unsigned)c;
        if (k != U64MAX) {
            unsigned a = (unsigned)((k >> 11) & 0x7FFu);
            unsigned b2 = (unsigned)(k & 0x7FFu);
            unsigned ca = comp[a], cb = comp[b2];
            unsigned c2 = (ca == (unsigned)c) ? cb : ca;
            p = c2;
            u64 k2 = atomicMin(&cbest[c2], U64MAX);
            if (!(k2 == k && c2 < (unsigned)c)) {   // mutual pick: smaller id adds
                unsigned li = atomicAdd(&cnt_s, 1u);
                deaths[base + li] = __uint_as_float((unsigned)(k >> 32));
            }
        }
        par[c] = p;
    }
    __syncthreads();
    // Phase 2: reset cbest; break 2-cycles (smaller root self-roots)
    #pragma unroll
    for (int c = t; c < B_N; c += 1024) {
        cbest[c] = U64MAX;
        unsigned p = par[c];
        if (p != (unsigned)c && par[p] == (unsigned)c && (unsigned)c < p) par[c] = (unsigned)c;
    }
    __syncthreads();
    // Pointer jumping (depth <= 2047 -> 11 iters)
    for (int it = 0; it < 11; ++it) {
        unsigned np0 = par[par[t]];
        unsigned np1 = par[par[t + 1024]];
        __syncthreads();
        par[t] = np0;
        par[t + 1024] = np1;
        __syncthreads();
    }
    // Relabel
    #pragma unroll
    for (int i = t; i < B_N; i += 1024) comp[i] = par[comp[i]];
    if (t == 0) {
        *gcnt = base + cnt_s;
        *(unsigned*)(ws + TICKET_OFF) = 0u;
    }
}

// out[e] = exp(-s0^2*c0^2) * sum_p exp(-s1^2*(rinv*death_p - c1)^2)
// Each block also reduces blo/bhi (4096 floats, L2-hot) -> rinv.
__global__ void __launch_bounds__(256) k_struct(const float* __restrict__ ws,
                                                const float* __restrict__ centres,
                                                const float* __restrict__ sharp,
                                                float* __restrict__ out) {
    const int e = blockIdx.x, t = threadIdx.x;
    const int lane = t & 63, wv = t >> 6;
    __shared__ float red[8];
    __shared__ float wsum[4];
    float lo = INFINITY, hi = -INFINITY;
    #pragma unroll
    for (int k = 0; k < 8; ++k) {
        int i = k * 256 + t;
        lo = fminf(lo, ws[BLO_OFF + i]);
        hi = fmaxf(hi, ws[BHI_OFF + i]);
    }
    #pragma unroll
    for (int off = 32; off; off >>= 1) {
        lo = fminf(lo, __shfl_down(lo, off));
        hi = fmaxf(hi, __shfl_down(hi, off));
    }
    if (lane == 0) { red[wv] = lo; red[wv + 4] = hi; }
    __syncthreads();
    lo = fminf(fminf(red[0], red[1]), fminf(red[2], red[3]));
    hi = fmaxf(fmaxf(red[4], red[5]), fmaxf(red[6], red[7]));
    float rng = hi - lo;
    float rinv = (rng > 1e-8f) ? 1.0f / rng : 0.0f;

    const float* deaths = ws + DEATHS_OFF;
    const float c0 = centres[e * 2], c1 = centres[e * 2 + 1];
    const float s0 = sharp[e * 2],   s1 = sharp[e * 2 + 1];
    const float s1sq = s1 * s1;
    float acc = 0.f;
    for (int p = t; p < B_N - 1; p += 256) {
        float d = deaths[p] * rinv - c1;
        acc += expf(-s1sq * d * d);
    }
    #pragma unroll
    for (int off = 32; off; off >>= 1) acc += __shfl_down(acc, off);
    if (lane == 0) wsum[wv] = acc;
    __syncthreads();
    if (t == 0) {
        float tot = wsum[0] + wsum[1] + wsum[2] + wsum[3];
        out[e] = expf(-s0 * s0 * c0 * c0) * tot;
    }
}

extern "C" void kernel_launch(void* const* d_in, const int* in_sizes, int n_in,
                              void* d_out, int out_size, void* d_ws, size_t ws_size,
                              hipStream_t stream) {
    const float* x       = (const float*)d_in[0];
    const float* centres = (const float*)d_in[1];
    const float* sharp   = (const float*)d_in[2];
    float* out = (float*)d_out;
    float* ws  = (float*)d_ws;

    hipLaunchKernelGGL(k_reduce, dim3(B_N),      dim3(256),    0, stream, x, ws);
    hipLaunchKernelGGL(k_dist,   dim3(128, 128), dim3(16, 16), 0, stream, ws);
    for (int r = 0; r < 11; ++r)
        hipLaunchKernelGGL(k_round, dim3(256), dim3(1024), 0, stream, ws);
    hipLaunchKernelGGL(k_struct, dim3(E_N), dim3(256), 0, stream, ws, centres, sharp, out);
}

// Round 5
// 196.068 us; speedup vs baseline: 1.8299x; 1.8299x over previous
//
#include <hip/hip_runtime.h>
#include <math.h>

// Problem constants
#define B_N 2048
#define T_N 128
#define C_N 3
#define J_N 25
#define E_N 64
#define TC  (T_N*C_N)    // 384 rows per batch
#define TCJ (TC*J_N)     // 9600 floats per batch
#define NQ4 (TCJ/4)      // 2400 float4 per batch

// Workspace layout (float offsets). Total ~16.3 MiB.
#define D_OFF      0                      // D [2048*2048] f32 (raw-h distances)
#define H_OFF      (B_N*B_N)              // h [2048*25] (raw)
#define BLO_OFF    (H_OFF + B_N*J_N)      // per-block lo [2048]
#define BHI_OFF    (BLO_OFF + B_N)        // per-block hi [2048]
#define COMP_OFF   (BHI_OFF + B_N)        // u32 comp[2048]
#define CNT_OFF    (COMP_OFF + B_N)       // u32 edge counter
#define DEATHS_OFF (CNT_OFF + 2)          // f32 deaths[2047] (pad keeps BEST_OFF even)
#define BEST_OFF   (DEATHS_OFF + B_N)     // u64 best[2048] (even offset -> 8B aligned)

typedef unsigned long long u64;
#define U64MAX 0xFFFFFFFFFFFFFFFFull

// One block per batch. Coalesced float4 grid-stride (stride 250 preserves
// j-residue mod 25), register accumulate, tiny LDS reduce. Also piggybacks
// MST state init and per-block lo/hi (no atomics needed).
__global__ void __launch_bounds__(256) k_reduce(const float* __restrict__ x,
                                                float* __restrict__ ws) {
    __shared__ float4 part[250];
    __shared__ float S[100];
    __shared__ float Mj[25];
    const int t = threadIdx.x, b = blockIdx.x;
    if (t == 0) {
        ((unsigned*)(ws + COMP_OFF))[b] = (unsigned)b;
        if (b == 0) *(unsigned*)(ws + CNT_OFF) = 0u;
    }
    const float4* x4 = (const float4*)(x + (size_t)b * TCJ);
    if (t < 250) {
        float4 a; a.x = a.y = a.z = a.w = 0.f;
        for (int idx = t; idx < NQ4; idx += 250) {
            float4 v = x4[idx];
            a.x += v.x; a.y += v.y; a.z += v.z; a.w += v.w;
        }
        part[t] = a;
    }
    __syncthreads();
    if (t < 25) {
        float4 s = part[t];
        #pragma unroll
        for (int g = 1; g < 10; ++g) {
            float4 v = part[t + 25 * g];
            s.x += v.x; s.y += v.y; s.z += v.z; s.w += v.w;
        }
        // S[k] = sum over batch of elements with flat index ≡ k (mod 100)
        S[4*t] = s.x; S[4*t+1] = s.y; S[4*t+2] = s.z; S[4*t+3] = s.w;
    }
    __syncthreads();
    if (t < 25) Mj[t] = (S[t] + S[t+25] + S[t+50] + S[t+75]) * (1.0f / 384.0f);
    __syncthreads();
    if (t < 25) {
        float mj = Mj[t], acc = 0.f;
        #pragma unroll
        for (int i = 0; i < J_N; ++i) { float d = Mj[i] - mj; acc += d * d; }
        float hv = sqrtf(acc);
        ws[H_OFF + b * J_N + t] = hv;
        S[t] = hv;
    }
    __syncthreads();
    if (t == 0) {
        float lo = S[0], hi = S[0];
        #pragma unroll
        for (int i = 1; i < J_N; ++i) { lo = fminf(lo, S[i]); hi = fmaxf(hi, S[i]); }
        ws[BLO_OFF + b] = lo;
        ws[BHI_OFF + b] = hi;
    }
}

// 16x16 tile of the 2048x2048 raw-h distance matrix per block.
// (Min-max normalization is the same affine map per coordinate -> distances
//  scale uniformly by rinv; MST is scale-invariant, rinv applied in k_struct.)
__global__ void k_dist(float* ws) {
    __shared__ float A[16][26], Bsh[16][26];
    const int tx = threadIdx.x, ty = threadIdx.y;
    const int flat = ty * 16 + tx;
    const int rowA = blockIdx.x * 16, rowB = blockIdx.y * 16;
    const float* h = ws + H_OFF;
    for (int idx = flat; idx < 16 * J_N; idx += 256) {
        int r = idx / J_N, c = idx % J_N;
        A[r][c]   = h[(rowA + r) * J_N + c];
        Bsh[r][c] = h[(rowB + r) * J_N + c];
    }
    __syncthreads();
    float acc = 0.f;
    #pragma unroll
    for (int k = 0; k < J_N; ++k) {
        float d = A[ty][k] - Bsh[tx][k];
        acc += d * d;
    }
    float* D = ws + D_OFF;
    D[(size_t)(rowA + ty) * B_N + rowB + tx] = sqrtf(fmaxf(acc, 1e-12f));
}

// Boruvka scan: one wave per row, min outgoing edge -> plain store best[row].
// NO global atomics, NO fences (round-4 lesson: same-address device atomics
// ping-pong across XCDs in late rounds). Key = (wbits<<32)|(min<<11)|max so
// both endpoints of an edge produce the identical, globally-distinct key.
__global__ void __launch_bounds__(1024) k_scan(float* __restrict__ ws) {
    if (*(const unsigned*)(ws + CNT_OFF) >= B_N - 1) return;  // converged
    const int t = threadIdx.x, w = t >> 6, lane = t & 63;
    const int row = blockIdx.x * 16 + w;
    const unsigned* comp = (const unsigned*)(ws + COMP_OFF);
    const unsigned ci = comp[row];
    const float4* row4 = (const float4*)(ws + D_OFF + (size_t)row * B_N);
    const uint4* comp4 = (const uint4*)comp;
    u64 best = U64MAX;
    #pragma unroll
    for (int k = 0; k < 8; ++k) {
        const int q = k * 64 + lane;          // float4 index within row
        float4 w4 = row4[q];
        uint4  c4 = comp4[q];
        const unsigned j0 = (unsigned)(q * 4);
        float wv[4] = {w4.x, w4.y, w4.z, w4.w};
        unsigned cv[4] = {c4.x, c4.y, c4.z, c4.w};
        #pragma unroll
        for (int m = 0; m < 4; ++m) {
            if (cv[m] != ci) {
                unsigned j = j0 + m;
                unsigned a = min((unsigned)row, j), b2 = max((unsigned)row, j);
                u64 key = ((u64)__float_as_uint(wv[m]) << 32) | (a << 11) | b2;
                if (key < best) best = key;
            }
        }
    }
    #pragma unroll
    for (int off = 32; off; off >>= 1) {
        u64 o = __shfl_down(best, off);
        if (o < best) best = o;
    }
    if (lane == 0) ((u64*)(ws + BEST_OFF))[row] = best;
}

// Boruvka union (single block): per-component min via LDS atomicMin (cheap,
// no cross-XCD traffic), then hook + dedup + 2-cycle break + pointer jump +
// relabel, all in LDS.
__global__ void __launch_bounds__(1024) k_union(float* __restrict__ ws) {
    unsigned* gcnt = (unsigned*)(ws + CNT_OFF);
    const unsigned base = *gcnt;
    if (base >= B_N - 1) return;  // converged
    __shared__ u64 cb[B_N];        // 16 KB: per-component best key
    __shared__ unsigned par[B_N];  // 8 KB
    __shared__ unsigned cnt_s;
    unsigned* comp = (unsigned*)(ws + COMP_OFF);
    const u64* best = (const u64*)(ws + BEST_OFF);
    float* deaths = ws + DEATHS_OFF;
    const int t = threadIdx.x;
    if (t == 0) cnt_s = 0u;
    cb[t] = U64MAX; cb[t + 1024] = U64MAX;
    __syncthreads();
    // Per-component min over node candidates (LDS atomics)
    #pragma unroll
    for (int i = t; i < B_N; i += 1024) {
        u64 bkey = best[i];
        if (bkey != U64MAX) atomicMin(&cb[comp[i]], bkey);
    }
    __syncthreads();
    // Hook + dedup + edge append
    #pragma unroll
    for (int c = t; c < B_N; c += 1024) {
        u64 k = cb[c];
        unsigned p = (unsigned)c;
        if (k != U64MAX) {
            unsigned a  = (unsigned)((k >> 11) & 0x7FFu);
            unsigned b2 = (unsigned)(k & 0x7FFu);
            unsigned ca = comp[a], cbv = comp[b2];
            unsigned c2 = (ca == (unsigned)c) ? cbv : ca;
            p = c2;
            if (!(cb[c2] == k && c2 < (unsigned)c)) {  // mutual pick: smaller id adds
                unsigned li = atomicAdd(&cnt_s, 1u);
                deaths[base + li] = __uint_as_float((unsigned)(k >> 32));
            }
        }
        par[c] = p;
    }
    __syncthreads();
    // Break 2-cycles (distinct keys -> hook graph has only 2-cycles)
    #pragma unroll
    for (int c = t; c < B_N; c += 1024) {
        unsigned p = par[c];
        if (p != (unsigned)c && par[p] == (unsigned)c && (unsigned)c < p) par[c] = (unsigned)c;
    }
    __syncthreads();
    // Pointer jumping (depth <= 2047 -> 11 iters)
    for (int it = 0; it < 11; ++it) {
        unsigned np0 = par[par[t]];
        unsigned np1 = par[par[t + 1024]];
        __syncthreads();
        par[t] = np0;
        par[t + 1024] = np1;
        __syncthreads();
    }
    // Relabel
    #pragma unroll
    for (int i = t; i < B_N; i += 1024) comp[i] = par[comp[i]];
    if (t == 0) *gcnt = base + cnt_s;
}

// out[e] = exp(-s0^2*c0^2) * sum_p exp(-s1^2*(rinv*death_p - c1)^2)
// Each block reduces blo/bhi (4096 floats, L2-hot) -> rinv.
__global__ void __launch_bounds__(256) k_struct(const float* __restrict__ ws,
                                                const float* __restrict__ centres,
                                                const float* __restrict__ sharp,
                                                float* __restrict__ out) {
    const int e = blockIdx.x, t = threadIdx.x;
    const int lane = t & 63, wv = t >> 6;
    __shared__ float red[8];
    __shared__ float wsum[4];
    float lo = INFINITY, hi = -INFINITY;
    #pragma unroll
    for (int k = 0; k < 8; ++k) {
        int i = k * 256 + t;
        lo = fminf(lo, ws[BLO_OFF + i]);
        hi = fmaxf(hi, ws[BHI_OFF + i]);
    }
    #pragma unroll
    for (int off = 32; off; off >>= 1) {
        lo = fminf(lo, __shfl_down(lo, off));
        hi = fmaxf(hi, __shfl_down(hi, off));
    }
    if (lane == 0) { red[wv] = lo; red[wv + 4] = hi; }
    __syncthreads();
    lo = fminf(fminf(red[0], red[1]), fminf(red[2], red[3]));
    hi = fmaxf(fmaxf(red[4], red[5]), fmaxf(red[6], red[7]));
    float rng = hi - lo;
    float rinv = (rng > 1e-8f) ? 1.0f / rng : 0.0f;

    const float* deaths = ws + DEATHS_OFF;
    const float c0 = centres[e * 2], c1 = centres[e * 2 + 1];
    const float s0 = sharp[e * 2],   s1 = sharp[e * 2 + 1];
    const float s1sq = s1 * s1;
    float acc = 0.f;
    for (int p = t; p < B_N - 1; p += 256) {
        float d = deaths[p] * rinv - c1;
        acc += expf(-s1sq * d * d);
    }
    #pragma unroll
    for (int off = 32; off; off >>= 1) acc += __shfl_down(acc, off);
    if (lane == 0) wsum[wv] = acc;
    __syncthreads();
    if (t == 0) {
        float tot = wsum[0] + wsum[1] + wsum[2] + wsum[3];
        out[e] = expf(-s0 * s0 * c0 * c0) * tot;
    }
}

extern "C" void kernel_launch(void* const* d_in, const int* in_sizes, int n_in,
                              void* d_out, int out_size, void* d_ws, size_t ws_size,
                              hipStream_t stream) {
    const float* x       = (const float*)d_in[0];
    const float* centres = (const float*)d_in[1];
    const float* sharp   = (const float*)d_in[2];
    float* out = (float*)d_out;
    float* ws  = (float*)d_ws;

    hipLaunchKernelGGL(k_reduce, dim3(B_N),      dim3(256),    0, stream, x, ws);
    hipLaunchKernelGGL(k_dist,   dim3(128, 128), dim3(16, 16), 0, stream, ws);
    for (int r = 0; r < 11; ++r) {
        hipLaunchKernelGGL(k_scan,  dim3(128), dim3(1024), 0, stream, ws);
        hipLaunchKernelGGL(k_union, dim3(1),   dim3(1024), 0, stream, ws);
    }
    hipLaunchKernelGGL(k_struct, dim3(E_N), dim3(256), 0, stream, ws, centres, sharp, out);
}